// Round 2
// baseline (348.375 us; speedup 1.0000x reference)
//
#include <hip/hip_runtime.h>
#include <cstdint>
#include <cstddef>

typedef __bf16 bf16x8 __attribute__((ext_vector_type(8)));
typedef float f32x4 __attribute__((ext_vector_type(4)));
typedef unsigned short u16;
typedef unsigned int u32;

static constexpr int T = 2048;
static constexpr int DM = 1024;
// 1/(32*ln2) = log2(e)/32 : folded into W_Q so attention needs only exp2
static constexpr float QSCALE = 0.04508422f;

#define GLOBAL_AS __attribute__((address_space(1)))
#define LDS_AS __attribute__((address_space(3)))

__device__ __forceinline__ void gld_lds16(const u16* g, u16* l) {
  __builtin_amdgcn_global_load_lds((const GLOBAL_AS u32*)g, (LDS_AS u32*)l, 16, 0, 0);
}

__device__ __forceinline__ u16 f2bf(float f) {
  u32 u = __builtin_bit_cast(u32, f);
  u += 0x7fffu + ((u >> 16) & 1u);
  return (u16)(u >> 16);
}

// pack two fp32 -> 2 bf16 in one dword
__device__ __forceinline__ u32 pkb(float lo, float hi) {
#if __has_builtin(__builtin_amdgcn_cvt_pk_bf16_f32)
  typedef __bf16 bf16x2 __attribute__((ext_vector_type(2)));
  bf16x2 r = __builtin_amdgcn_cvt_pk_bf16_f32(lo, hi);
  return __builtin_bit_cast(u32, r);
#else
  return __builtin_amdgcn_perm(__builtin_bit_cast(u32, hi),
                               __builtin_bit_cast(u32, lo), 0x07060302u);
#endif
}

__device__ __forceinline__ float fexp2(float x) {
#if __has_builtin(__builtin_amdgcn_exp2f)
  return __builtin_amdgcn_exp2f(x);
#else
  return __builtin_exp2f(x);
#endif
}

__device__ __forceinline__ void pl16swap(u32& a, u32& b) {
  asm("v_permlane16_swap_b32 %0, %1" : "+v"(a), "+v"(b));
}
__device__ __forceinline__ void pl32swap(u32& a, u32& b) {
  asm("v_permlane32_swap_b32 %0, %1" : "+v"(a), "+v"(b));
}

// ---------------- X fp32 -> bf16 convert (once) ---------------------------------------
__global__ __launch_bounds__(256) void xcvt(
    const float* __restrict__ q, const float* __restrict__ k, const float* __restrict__ v,
    u16* __restrict__ oq, u16* __restrict__ ok, u16* __restrict__ ov) {
  const float* X = blockIdx.y == 0 ? q : blockIdx.y == 1 ? k : v;
  u16* O = blockIdx.y == 0 ? oq : blockIdx.y == 1 ? ok : ov;
  const size_t i = ((size_t)blockIdx.x * 256 + threadIdx.x) * 8;
  float4 a0 = *(const float4*)(X + i), a1 = *(const float4*)(X + i + 4);
  uint4 p;
  p.x = pkb(a0.x, a0.y); p.y = pkb(a0.z, a0.w);
  p.z = pkb(a1.x, a1.y); p.w = pkb(a1.z, a1.w);
  *(uint4*)(O + i) = p;
}

// ---------------- Weight transpose + convert: Wt[n][k] bf16 from W[k][n] fp32 --------
__global__ __launch_bounds__(256) void wt_kernel(
    const float* __restrict__ W0, const float* __restrict__ W1, const float* __restrict__ W2,
    u16* __restrict__ O0, u16* __restrict__ O1, u16* __restrict__ O2) {
  const float* W = blockIdx.z == 0 ? W0 : blockIdx.z == 1 ? W1 : W2;
  u16* O = blockIdx.z == 0 ? O0 : blockIdx.z == 1 ? O1 : O2;
  const float sc = blockIdx.z == 0 ? QSCALE : 1.0f;
  const int k0 = blockIdx.x * 64, n0 = blockIdx.y * 64;
  __shared__ float tile[64][68];
  const int tid = threadIdx.x;
#pragma unroll
  for (int it = 0; it < 4; ++it) {
    int chunk = tid + it * 256;
    int r = chunk >> 4, c4 = (chunk & 15) * 4;
    *(float4*)&tile[r][c4] = *(const float4*)(W + (size_t)(k0 + r) * DM + n0 + c4);
  }
  __syncthreads();
#pragma unroll
  for (int it = 0; it < 4; ++it) {
    int chunk = tid + it * 256;
    int n = chunk >> 4, k4 = (chunk & 15) * 4;
    ushort4 o;
    o.x = f2bf(tile[k4 + 0][n] * sc);
    o.y = f2bf(tile[k4 + 1][n] * sc);
    o.z = f2bf(tile[k4 + 2][n] * sc);
    o.w = f2bf(tile[k4 + 3][n] * sc);
    *(ushort4*)(O + (size_t)(n0 + n) * DM + k0 + k4) = o;
  }
}

// ---------------- Projection GEMM, 8-phase 256x256 schedule (T2+T3+T4+T5) -------------
// 512 thr = 8 waves (2M x 4N), per-wave 128x64 out, BK=64, LDS 128KB (2-buf A+B).
// Per K-tile: 4 phases, each = [reads | stage | (vmcnt)] barrier [16 MFMA @prio1] barrier.
// Quadrant order (mq,nq) = (0,0),(0,1),(1,1),(1,0) so af reloads once, bfA/bfB held.
// Staging: tile t+1's A at t.P0, B at t.P1 (3-4 phase lead, ~1200cy > HBM 900cy).
// Single counted vmcnt(4) per tile at P0: queue=[A(t),B(t),A(t+1)] -> tile t complete,
// A(t+1) stays in flight. vmcnt(0) only on the last tile.
__global__ __launch_bounds__(512, 2) void gemm8(
    const u16* __restrict__ Xq, const u16* __restrict__ Xk, const u16* __restrict__ Xv,
    const u16* __restrict__ Wq, const u16* __restrict__ Wk, const u16* __restrict__ Wv,
    u16* __restrict__ Oq, u16* __restrict__ Ok, u16* __restrict__ VHt) {
  extern __shared__ u16 lds[];                  // 131072 B: A[2][256][64] | B[2][256][64]
  const int blk0 = blockIdx.x;                  // 0..383
  const int swz = (blk0 & 7) * 48 + (blk0 >> 3);  // bijective XCD chunking (384%8==0)
  const int z = swz >> 7;                       // 0..2
  const int rr = swz & 127;
  const int n0 = (rr & 3) * 256;
  const int m0 = (rr >> 2) * 256;
  const u16* X = z == 0 ? Xq : z == 1 ? Xk : Xv;   // [8192][1024] bf16
  const u16* W = z == 0 ? Wq : z == 1 ? Wk : Wv;   // [1024][1024] bf16 (N-major, K rows)
  const int tid = threadIdx.x, w = tid >> 6, lane = tid & 63;
  const int c16 = lane & 15, quad = lane >> 4;
  const int wm2 = w >> 2, wn4 = w & 3;          // wave tile: rows wm2*128, cols wn4*64
  const int rk = lane >> 3;
  const int ck = ((lane & 7) ^ rk) * 8;         // pre-swizzled global chunk
  const int swzr = c16 & 7;
  u16* As = lds;                                // [2][256][64]
  u16* Bs = lds + 2 * 256 * 64;
  f32x4 acc[8][4] = {};                         // m-frag i: row i*16 ; n-frag j: col j*16
  const u16* gA = X + (size_t)(m0 + w * 8 + rk) * DM + ck;
  const u16* gB = W + (size_t)(n0 + w * 8 + rk) * DM + ck;
  // prologue: stage tile 0 into buf 0 (A then B: queue order matters for vmcnt math)
#pragma unroll
  for (int u = 0; u < 4; ++u)
    gld_lds16(gA + (size_t)(u * 64) * DM, As + (u * 64 + w * 8) * 64);
#pragma unroll
  for (int u = 0; u < 4; ++u)
    gld_lds16(gB + (size_t)(u * 64) * DM, Bs + (u * 64 + w * 8) * 64);

  bf16x8 af[4][2], bfA[2][2], bfB[2][2];
  for (int kt = 0; kt < 16; ++kt) {
    const int p = kt & 1, tn = kt + 1;
    const u16* Ab = As + p * 16384;
    const u16* Bb = Bs + p * 16384;
    u16* An = As + (p ^ 1) * 16384;
    u16* Bn = Bs + (p ^ 1) * 16384;
    // ---- P0: stage A(t+1); vmcnt; BAR; read af(mq0)+bfA(nq0); MFMA Q(0,0); BAR ----
    if (tn < 16) {
      const size_t ko = (size_t)tn * 64;
#pragma unroll
      for (int u = 0; u < 4; ++u)
        gld_lds16(gA + (size_t)(u * 64) * DM + ko, An + (u * 64 + w * 8) * 64);
      asm volatile("s_waitcnt vmcnt(4)" ::: "memory");
    } else {
      asm volatile("s_waitcnt vmcnt(0)" ::: "memory");
    }
    __builtin_amdgcn_s_barrier();
#pragma unroll
    for (int f = 0; f < 4; ++f) {
      const int R = wm2 * 128 + f * 16 + c16;
      af[f][0] = *(const bf16x8*)&Ab[R * 64 + ((quad    ) ^ swzr) * 8];
      af[f][1] = *(const bf16x8*)&Ab[R * 64 + ((quad + 4) ^ swzr) * 8];
    }
#pragma unroll
    for (int g = 0; g < 2; ++g) {
      const int R = wn4 * 64 + g * 16 + c16;
      bfA[g][0] = *(const bf16x8*)&Bb[R * 64 + ((quad    ) ^ swzr) * 8];
      bfA[g][1] = *(const bf16x8*)&Bb[R * 64 + ((quad + 4) ^ swzr) * 8];
    }
    __builtin_amdgcn_s_setprio(1);
#pragma unroll
    for (int f = 0; f < 4; ++f)
#pragma unroll
      for (int g = 0; g < 2; ++g) {
        acc[f][g] = __builtin_amdgcn_mfma_f32_16x16x32_bf16(af[f][0], bfA[g][0], acc[f][g], 0, 0, 0);
        acc[f][g] = __builtin_amdgcn_mfma_f32_16x16x32_bf16(af[f][1], bfA[g][1], acc[f][g], 0, 0, 0);
      }
    __builtin_amdgcn_s_setprio(0);
    __builtin_amdgcn_s_barrier();
    // ---- P1: read bfB(nq1); stage B(t+1); BAR; MFMA Q(0,1); BAR ----
#pragma unroll
    for (int g = 0; g < 2; ++g) {
      const int R = wn4 * 64 + 32 + g * 16 + c16;
      bfB[g][0] = *(const bf16x8*)&Bb[R * 64 + ((quad    ) ^ swzr) * 8];
      bfB[g][1] = *(const bf16x8*)&Bb[R * 64 + ((quad + 4) ^ swzr) * 8];
    }
    if (tn < 16) {
      const size_t ko = (size_t)tn * 64;
#pragma unroll
      for (int u = 0; u < 4; ++u)
        gld_lds16(gB + (size_t)(u * 64) * DM + ko, Bn + (u * 64 + w * 8) * 64);
    }
    __builtin_amdgcn_s_barrier();
    __builtin_amdgcn_s_setprio(1);
#pragma unroll
    for (int f = 0; f < 4; ++f)
#pragma unroll
      for (int g = 0; g < 2; ++g) {
        acc[f][2 + g] = __builtin_amdgcn_mfma_f32_16x16x32_bf16(af[f][0], bfB[g][0], acc[f][2 + g], 0, 0, 0);
        acc[f][2 + g] = __builtin_amdgcn_mfma_f32_16x16x32_bf16(af[f][1], bfB[g][1], acc[f][2 + g], 0, 0, 0);
      }
    __builtin_amdgcn_s_setprio(0);
    __builtin_amdgcn_s_barrier();
    // ---- P2: read af(mq1); BAR; MFMA Q(1,1); BAR ----
#pragma unroll
    for (int f = 0; f < 4; ++f) {
      const int R = wm2 * 128 + 64 + f * 16 + c16;
      af[f][0] = *(const bf16x8*)&Ab[R * 64 + ((quad    ) ^ swzr) * 8];
      af[f][1] = *(const bf16x8*)&Ab[R * 64 + ((quad + 4) ^ swzr) * 8];
    }
    __builtin_amdgcn_s_barrier();
    __builtin_amdgcn_s_setprio(1);
#pragma unroll
    for (int f = 0; f < 4; ++f)
#pragma unroll
      for (int g = 0; g < 2; ++g) {
        acc[4 + f][2 + g] = __builtin_amdgcn_mfma_f32_16x16x32_bf16(af[f][0], bfB[g][0], acc[4 + f][2 + g], 0, 0, 0);
        acc[4 + f][2 + g] = __builtin_amdgcn_mfma_f32_16x16x32_bf16(af[f][1], bfB[g][1], acc[4 + f][2 + g], 0, 0, 0);
      }
    __builtin_amdgcn_s_setprio(0);
    __builtin_amdgcn_s_barrier();
    // ---- P3: MFMA Q(1,0) from held regs; BAR; BAR ----
    __builtin_amdgcn_s_barrier();
    __builtin_amdgcn_s_setprio(1);
#pragma unroll
    for (int f = 0; f < 4; ++f)
#pragma unroll
      for (int g = 0; g < 2; ++g) {
        acc[4 + f][g] = __builtin_amdgcn_mfma_f32_16x16x32_bf16(af[f][0], bfA[g][0], acc[4 + f][g], 0, 0, 0);
        acc[4 + f][g] = __builtin_amdgcn_mfma_f32_16x16x32_bf16(af[f][1], bfA[g][1], acc[4 + f][g], 0, 0, 0);
      }
    __builtin_amdgcn_s_setprio(0);
    __builtin_amdgcn_s_barrier();
  }
  // epilogue: acc[i][j] -> rows m0 + wm2*128 + i*16 + quad*4 + r, cols n0 + wn4*64 + j*16 + c16
  if (z < 2) {
    u16* O = z == 0 ? Oq : Ok;
#pragma unroll
    for (int i = 0; i < 8; ++i)
#pragma unroll
      for (int j = 0; j < 4; ++j)
#pragma unroll
        for (int r = 0; r < 4; ++r) {
          size_t row = m0 + wm2 * 128 + i * 16 + quad * 4 + r;
          size_t col = n0 + wn4 * 64 + j * 16 + c16;
          O[row * DM + col] = f2bf(acc[i][j][r]);
        }
  } else {
    // V slice: write transposed VHt[bh][d][t]; the 4 r-values are consecutive t.
#pragma unroll
    for (int i = 0; i < 8; ++i)
#pragma unroll
      for (int j = 0; j < 4; ++j) {
        const int row0 = m0 + wm2 * 128 + i * 16 + quad * 4;
        const int col = n0 + wn4 * 64 + j * 16 + c16;
        const int bb = row0 >> 11, t0 = row0 & 2047;
        const int hh = col >> 6, dd = col & 63;
        ushort4 o;
        o.x = f2bf(acc[i][j][0]);
        o.y = f2bf(acc[i][j][1]);
        o.z = f2bf(acc[i][j][2]);
        o.w = f2bf(acc[i][j][3]);
        *(ushort4*)(VHt + ((size_t)((bb * 16 + hh) * 64 + dd)) * T + t0) = o;
      }
  }
}

// ---------------- Flash attention + residual, S^T form, permlane P-exchange ----------
// v7 = v6 + T5 setprio around MFMA clusters (m191: +4-7% attn). Structure unchanged.
__global__ __launch_bounds__(256, 4) void flash_kernel(
    const u16* __restrict__ QH, const u16* __restrict__ KH, const u16* __restrict__ VHt,
    const float* __restrict__ res, float* __restrict__ out) {
  const int blk = blockIdx.x;
  const int x = blk & 7, g = blk >> 3;
  const int bh = x * 8 + (g & 7);          // XCD x owns heads 8x..8x+7 (K/V ~4MB = L2)
  const int qb = g >> 3;                   // 0..15, 128 q-rows each
  const int b = bh >> 4, h = bh & 15;
  const int tid = threadIdx.x, w = tid >> 6, lane = tid & 63;
  const int c16 = lane & 15, quad = lane >> 4;
  const int swzq = c16 & 7;
  __shared__ u16 Kl[2][64][64];            // [buf][k][d], chunk c of row r at c^(r&7)
  __shared__ u16 Vt[2][64][64];            // [buf][d][k], same swizzle
  __shared__ float Ll[4][2][16];
  const int qbase = qb * 128 + w * 32;
  bf16x8 bq[2][2];                         // B-frags of Q (resident)
#pragma unroll
  for (int qi = 0; qi < 2; ++qi) {
    const u16* qp = QH + (size_t)(b * T + qbase + qi * 16 + c16) * DM + h * 64 + quad * 8;
    bq[qi][0] = *(const bf16x8*)qp;
    bq[qi][1] = *(const bf16x8*)(qp + 32);
  }
  f32x4 acc[2][4] = {};                    // [qi][nt]
  float rs[2] = {0.f, 0.f};
  const int rk = lane >> 3;
  const int ck8 = ((lane & 7) ^ rk) * 8;
  const u16* kg = KH + (size_t)(b * T) * DM + h * 64 + ck8;
  const u16* vg = VHt + ((size_t)bh * 64 + w * 16 + rk) * T + ck8;
  // prologue: stage tile 0 into buf 0 (4 outstanding vmem per wave)
  {
    const u16* kg0 = kg + (size_t)(w * 16 + rk) * DM;
    gld_lds16(kg0, &Kl[0][w * 16][0]);
    gld_lds16(kg0 + (size_t)8 * DM, &Kl[0][w * 16 + 8][0]);
    gld_lds16(vg, &Vt[0][w * 16][0]);
    gld_lds16(vg + 8 * T, &Vt[0][w * 16 + 8][0]);
  }
  int cur = 0;
  for (int kt = 0; kt < 32; ++kt) {
    // B1: everyone finished reading buf[cur^1]
    __builtin_amdgcn_s_barrier();
    if (kt < 31) {
      const u16* kg0 = kg + (size_t)((kt + 1) * 64 + w * 16 + rk) * DM;
      gld_lds16(kg0, &Kl[cur ^ 1][w * 16][0]);
      gld_lds16(kg0 + (size_t)8 * DM, &Kl[cur ^ 1][w * 16 + 8][0]);
      const u16* vg0 = vg + (kt + 1) * 64;
      gld_lds16(vg0, &Vt[cur ^ 1][w * 16][0]);
      gld_lds16(vg0 + (size_t)8 * T, &Vt[cur ^ 1][w * 16 + 8][0]);
      asm volatile("s_waitcnt vmcnt(4)" ::: "memory");  // tile kt landed; kt+1 in flight
    } else {
      asm volatile("s_waitcnt vmcnt(0)" ::: "memory");  // final tile: drain
    }
    // B2: all waves' buf[cur] stages visible
    __builtin_amdgcn_s_barrier();
    // ---- Phase A: S^T = K Q^T, exp2, permlane quad-exchange -> PV A-frags ----
    bf16x8 ap[2][2];
    {
      bf16x8 ak[4][2];
#pragma unroll
      for (int mt = 0; mt < 4; ++mt) {
        const int r = mt * 16 + c16;
        ak[mt][0] = *(const bf16x8*)&Kl[cur][r][(quad ^ swzq) * 8];
        ak[mt][1] = *(const bf16x8*)&Kl[cur][r][((4 + quad) ^ swzq) * 8];
      }
#pragma unroll
      for (int qi = 0; qi < 2; ++qi) {
        u32 d[2][2][2];                    // [mt1][mt0][jd], all indices static
#pragma unroll
        for (int mt = 0; mt < 4; ++mt) {
          f32x4 st = {};
          __builtin_amdgcn_s_setprio(1);
          st = __builtin_amdgcn_mfma_f32_16x16x32_bf16(ak[mt][0], bq[qi][0], st, 0, 0, 0);
          st = __builtin_amdgcn_mfma_f32_16x16x32_bf16(ak[mt][1], bq[qi][1], st, 0, 0, 0);
          __builtin_amdgcn_s_setprio(0);
          const float p0 = fexp2(st[0]), p1 = fexp2(st[1]);
          const float p2 = fexp2(st[2]), p3 = fexp2(st[3]);
          rs[qi] += (p0 + p1) + (p2 + p3);
          d[mt >> 1][mt & 1][0] = pkb(p0, p1);
          d[mt >> 1][mt & 1][1] = pkb(p2, p3);
        }
        // transpose (lane bit5 <-> reg bit mt0)
        pl32swap(d[0][0][0], d[0][1][0]);
        pl32swap(d[0][0][1], d[0][1][1]);
        pl32swap(d[1][0][0], d[1][1][0]);
        pl32swap(d[1][0][1], d[1][1][1]);
        // transpose (lane bit4 <-> reg bit mt0)
        pl16swap(d[0][0][0], d[0][1][0]);
        pl16swap(d[0][0][1], d[0][1][1]);
        pl16swap(d[1][0][0], d[1][1][0]);
        pl16swap(d[1][0][1], d[1][1][1]);
        // now d[h][e][jd] holds k = 32h + quad*8 + 4e + 2jd (+0,1) for q=qi*16+c16
        uint4 a0 = {d[0][0][0], d[0][0][1], d[0][1][0], d[0][1][1]};
        uint4 a1 = {d[1][0][0], d[1][0][1], d[1][1][0], d[1][1][1]};
        ap[qi][0] = __builtin_bit_cast(bf16x8, a0);
        ap[qi][1] = __builtin_bit_cast(bf16x8, a1);
      }
    }
    // ---- Phase B: O += P V (pure register dataflow from phase A) ----
#pragma unroll
    for (int nt = 0; nt < 4; ++nt) {
      const int r = nt * 16 + c16;
      const bf16x8 bv0 = *(const bf16x8*)&Vt[cur][r][(quad ^ swzq) * 8];
      const bf16x8 bv1 = *(const bf16x8*)&Vt[cur][r][((4 + quad) ^ swzq) * 8];
      __builtin_amdgcn_s_setprio(1);
#pragma unroll
      for (int qi = 0; qi < 2; ++qi) {
        acc[qi][nt] = __builtin_amdgcn_mfma_f32_16x16x32_bf16(ap[qi][0], bv0, acc[qi][nt], 0, 0, 0);
        acc[qi][nt] = __builtin_amdgcn_mfma_f32_16x16x32_bf16(ap[qi][1], bv1, acc[qi][nt], 0, 0, 0);
      }
      __builtin_amdgcn_s_setprio(0);
    }
    cur ^= 1;
  }
  // softmax denominators: reduce over quads, broadcast via LDS (per-wave, no barrier)
#pragma unroll
  for (int qi = 0; qi < 2; ++qi) {
    float t = rs[qi];
    t += __shfl_xor(t, 16, 64);
    t += __shfl_xor(t, 32, 64);
    if (quad == 0) Ll[w][qi][c16] = t;
  }
  asm volatile("s_waitcnt lgkmcnt(0)" ::: "memory");
#pragma unroll
  for (int qi = 0; qi < 2; ++qi) {
    const f32x4 lv = *(const f32x4*)&Ll[w][qi][quad * 4];
#pragma unroll
    for (int r = 0; r < 4; ++r) {
      const float inv = 1.0f / lv[r];
      const size_t rowbase = (size_t)(b * T + qbase + qi * 16 + quad * 4 + r) * DM + h * 64;
#pragma unroll
      for (int nt = 0; nt < 4; ++nt) {
        const size_t idx = rowbase + nt * 16 + c16;
        out[idx] = acc[qi][nt][r] * inv + res[idx];
      }
    }
  }
}

extern "C" void kernel_launch(void* const* d_in, const int* in_sizes, int n_in,
                              void* d_out, int out_size, void* d_ws, size_t ws_size,
                              hipStream_t stream) {
  const float* q = (const float*)d_in[0];
  const float* k = (const float*)d_in[1];
  const float* v = (const float*)d_in[2];
  const float* WQ = (const float*)d_in[3];
  const float* WK = (const float*)d_in[4];
  const float* WV = (const float*)d_in[5];
  char* ws = (char*)d_ws;
  const size_t PH = (size_t)8192 * 1024 * 2;   // bf16 activation buffer bytes
  const size_t WT = (size_t)1024 * 1024 * 2;
  // d_out doubles as scratch for 2 of the 3 bf16 X tensors (fully rewritten by flash).
  u16* XqB = (u16*)d_out;
  u16* XkB = (u16*)d_out + (size_t)8192 * 1024;
  u16* XvB = (u16*)(ws);
  u16* WtQ = (u16*)(ws + PH);
  u16* WtK = (u16*)(ws + PH + WT);
  u16* WtV = (u16*)(ws + PH + 2 * WT);
  u16* QH  = (u16*)(ws + PH + 3 * WT);
  u16* KH  = (u16*)(ws + 2 * PH + 3 * WT);
  u16* VHt = (u16*)(ws + 3 * PH + 3 * WT);

  // 128 KiB dynamic LDS for gemm8 (above the 64 KiB default cap)
  hipFuncSetAttribute(reinterpret_cast<const void*>(gemm8),
                      hipFuncAttributeMaxDynamicSharedMemorySize, 131072);

  xcvt<<<dim3(4096, 3), 256, 0, stream>>>(q, k, v, XqB, XkB, XvB);
  wt_kernel<<<dim3(16, 16, 3), 256, 0, stream>>>(WQ, WK, WV, WtQ, WtK, WtV);
  gemm8<<<dim3(384), 512, 131072, stream>>>(XqB, XkB, XvB, WtQ, WtK, WtV, QH, KH, VHt);
  flash_kernel<<<1024, 256, 0, stream>>>(QH, KH, VHt, q, (float*)d_out);
}